// Round 1
// baseline (265.529 us; speedup 1.0000x reference)
//
#include <hip/hip_runtime.h>

// Problem constants (fixed by setup_inputs): N=2048, B=64, H=W=4096, ks=8
#define GRIDN 64        // block positions per axis (H/B)
#define NCELLS 4096     // GRIDN*GRIDN
#define BVEC 8192       // float4 per block: 64*64*8/4
#define ROWSTRIDE4 8192 // float4 per dense row: W*ks/4 = 4096*8/4

// ws layout (int32 units)
#define WS_FLAG 0       // 1 int: 1 if indices are int64
#define WS_OFFS 16      // 4097 ints: exclusive CSR offsets
#define WS_COUNTS 8192  // 4096 ints
#define WS_LIST 16384   // N ints, then cellid N ints after

// ---------------------------------------------------------------------------
// Kernel A: zero the per-cell counts and detect index dtype.
// int64 little-endian with values in [0,64) => every odd 32-bit word of the
// first 2*N words is zero. int32 real data: odd words are column indices.
__global__ void k_detect_zero(const int* __restrict__ idx_words, int nwords,
                              int* __restrict__ ws_i) {
    __shared__ int any_nonzero;
    if (threadIdx.x == 0) any_nonzero = 0;
    __syncthreads();
    for (int i = threadIdx.x; i < NCELLS; i += blockDim.x)
        ws_i[WS_COUNTS + i] = 0;
    int local = 0;
    for (int i = 1 + 2 * (int)threadIdx.x; i < nwords; i += 2 * (int)blockDim.x)
        if (idx_words[i] != 0) local = 1;
    if (local) any_nonzero = 1;  // benign race, all write 1
    __syncthreads();
    if (threadIdx.x == 0) ws_i[WS_FLAG] = (any_nonzero == 0) ? 1 : 0;
}

// ---------------------------------------------------------------------------
// Kernel B: per-block cell id + count histogram.
__global__ void k_count(const void* __restrict__ idx, int N,
                        int* __restrict__ ws_i, int* __restrict__ cellid) {
    int n = blockIdx.x * blockDim.x + threadIdx.x;
    if (n >= N) return;
    int f64 = ws_i[WS_FLAG];
    int r, c;
    if (f64) {
        const long long* p = (const long long*)idx;
        r = (int)p[2 * n];
        c = (int)p[2 * n + 1];
    } else {
        const int* p = (const int*)idx;
        r = p[2 * n];
        c = p[2 * n + 1];
    }
    int cell = -1;
    if (r >= 0 && r < GRIDN && c >= 0 && c < GRIDN) {
        cell = r * GRIDN + c;
        atomicAdd(&ws_i[WS_COUNTS + cell], 1);
    }
    cellid[n] = cell;
}

// ---------------------------------------------------------------------------
// Kernel C: exclusive scan of 4096 counts -> offsets[4097]. One workgroup.
__global__ void k_scan(int* __restrict__ ws_i) {
    __shared__ int buf[2][NCELLS];
    int* counts = ws_i + WS_COUNTS;
    int* offsets = ws_i + WS_OFFS;
    int tid = threadIdx.x;  // 1024 threads
    for (int i = tid; i < NCELLS; i += 1024) buf[0][i] = counts[i];
    __syncthreads();
    int src = 0;
    for (int d = 1; d < NCELLS; d <<= 1) {
        for (int i = tid; i < NCELLS; i += 1024) {
            int v = buf[src][i];
            if (i >= d) v += buf[src][i - d];
            buf[src ^ 1][i] = v;
        }
        __syncthreads();
        src ^= 1;
    }
    for (int i = tid; i < NCELLS; i += 1024) offsets[i + 1] = buf[src][i];
    if (tid == 0) offsets[0] = 0;
}

// ---------------------------------------------------------------------------
// Kernel D: deterministic fill — rank of n among same-cell blocks with m < n.
__global__ void k_fill(const int* __restrict__ cellid, int N,
                       const int* __restrict__ offsets, int* __restrict__ list) {
    int n = blockIdx.x * blockDim.x + threadIdx.x;
    if (n >= N) return;
    int cell = cellid[n];
    if (cell < 0) return;
    int rank = 0;
    for (int m = 0; m < n; ++m) rank += (cellid[m] == cell) ? 1 : 0;
    list[offsets[cell] + rank] = n;
}

// ---------------------------------------------------------------------------
// Kernel E: dense gather. grid = (4 chunks, 4096 cells), 256 threads.
// Each thread accumulates 8 float4 (one cell = 8192 float4 = 64 rows x 128).
__global__ __launch_bounds__(256) void k_dense(const float4* __restrict__ bv4,
                                               const int* __restrict__ offsets,
                                               const int* __restrict__ list,
                                               float4* __restrict__ out4) {
    const int cell = blockIdx.y;
    const int R = cell >> 6;
    const int C = cell & (GRIDN - 1);
    const int start = offsets[cell];
    const int end = offsets[cell + 1];
    const int tbase = blockIdx.x * 2048 + threadIdx.x;

    float4 acc[8];
#pragma unroll
    for (int i = 0; i < 8; ++i) acc[i] = make_float4(0.f, 0.f, 0.f, 0.f);

    for (int j = start; j < end; ++j) {
        const float4* __restrict__ src = bv4 + (size_t)list[j] * BVEC;
#pragma unroll
        for (int i = 0; i < 8; ++i) {
            float4 v = src[tbase + i * 256];
            acc[i].x += v.x;
            acc[i].y += v.y;
            acc[i].z += v.z;
            acc[i].w += v.w;
        }
    }
#pragma unroll
    for (int i = 0; i < 8; ++i) {
        int t = tbase + i * 256;
        int row = t >> 7;
        int slot = t & 127;
        out4[(size_t)(R * 64 + row) * ROWSTRIDE4 + (size_t)(C * 128 + slot)] = acc[i];
    }
}

// ---------------------------------------------------------------------------
extern "C" void kernel_launch(void* const* d_in, const int* in_sizes, int n_in,
                              void* d_out, int out_size, void* d_ws, size_t ws_size,
                              hipStream_t stream) {
    const float* bv = (const float*)d_in[0];
    const void* idx = d_in[1];
    const int N = in_sizes[1] / 2;  // 2048 blocks

    float* out = (float*)d_out;
    int* ws_i = (int*)d_ws;
    int* offsets = ws_i + WS_OFFS;
    int* list = ws_i + WS_LIST;
    int* cellid = ws_i + WS_LIST + N;

    k_detect_zero<<<1, 1024, 0, stream>>>((const int*)idx, 2 * N, ws_i);
    k_count<<<(N + 255) / 256, 256, 0, stream>>>(idx, N, ws_i, cellid);
    k_scan<<<1, 1024, 0, stream>>>(ws_i);
    k_fill<<<(N + 255) / 256, 256, 0, stream>>>(cellid, N, offsets, list);

    dim3 grid(4, NCELLS);
    k_dense<<<grid, 256, 0, stream>>>((const float4*)bv, offsets, list,
                                      (float4*)out);
}

// Round 2
// 261.533 us; speedup vs baseline: 1.0153x; 1.0153x over previous
//
#include <hip/hip_runtime.h>

// Problem constants (fixed by setup_inputs): N=2048, B=64, H=W=4096, ks=8
#define GRIDN 64        // block positions per axis (H/B)
#define NCELLS 4096     // GRIDN*GRIDN
#define BVEC 8192       // float4 per block: 64*64*8/4
#define ROWSTRIDE4 8192 // float4 per dense row: W*ks/4

// ws layout (int32 units)
#define WS_OFFS 16      // 4097 ints: exclusive CSR offsets
#define WS_LIST 8192    // N ints: block ids grouped by cell

typedef float f32x4 __attribute__((ext_vector_type(4)));

// ---------------------------------------------------------------------------
// Fused setup: dtype-detect + cellid + histogram + scan + deterministic rank.
// One workgroup, 1024 threads; counts/cellid live entirely in LDS.
__global__ __launch_bounds__(1024) void k_setup(const void* __restrict__ idx,
                                                int N, int* __restrict__ ws_i) {
    __shared__ int buf[2][NCELLS];       // 32 KB: histogram + scan
    __shared__ short cellid_s[2048];     // 4 KB
    __shared__ int f64_s;
    const int tid = threadIdx.x;

    // int64 little-endian with values in [0,64): every odd 32-bit word of the
    // first 2N words is a zero high-half. int32: odd words are col indices.
    const int* w = (const int*)idx;
    int local = 0;
    for (int i = 1 + 2 * tid; i < 2 * N; i += 2 * 1024) local |= (w[i] != 0);
    if (tid == 0) f64_s = 0;
    for (int i = tid; i < NCELLS; i += 1024) buf[0][i] = 0;
    __syncthreads();
    if (local) f64_s = 1;  // benign race, all write 1
    __syncthreads();
    const int is64 = (f64_s == 0);

    // cellid + LDS histogram
    for (int n = tid; n < N; n += 1024) {
        int r, c;
        if (is64) {
            const long long* p = (const long long*)idx;
            r = (int)p[2 * n];
            c = (int)p[2 * n + 1];
        } else {
            const int* p = (const int*)idx;
            r = p[2 * n];
            c = p[2 * n + 1];
        }
        int cell = (r >= 0 && r < GRIDN && c >= 0 && c < GRIDN) ? r * GRIDN + c : -1;
        cellid_s[n] = (short)cell;
        if (cell >= 0) atomicAdd(&buf[0][cell], 1);
    }
    __syncthreads();

    // Hillis-Steele inclusive scan of counts
    int src = 0;
    for (int d = 1; d < NCELLS; d <<= 1) {
        for (int i = tid; i < NCELLS; i += 1024) {
            int v = buf[src][i];
            if (i >= d) v += buf[src][i - d];
            buf[src ^ 1][i] = v;
        }
        __syncthreads();
        src ^= 1;
    }
    for (int i = tid; i < NCELLS; i += 1024) ws_i[WS_OFFS + i + 1] = buf[src][i];
    if (tid == 0) ws_i[WS_OFFS] = 0;

    // Deterministic rank: #{m < n : cellid[m] == cellid[n]} (LDS-resident)
    for (int n = tid; n < N; n += 1024) {
        int cell = cellid_s[n];
        if (cell < 0) continue;
        int rank = 0;
        for (int m = 0; m < n; ++m) rank += (cellid_s[m] == cell) ? 1 : 0;
        int off = (cell == 0) ? 0 : buf[src][cell - 1];  // exclusive offset
        ws_i[WS_LIST + off + rank] = n;
    }
}

// ---------------------------------------------------------------------------
// Dense gather: 16384 wgs = 4 chunks x 4096 cells, 256 threads, 8 float4/thread.
// Specialized paths: 0 blocks (zero-fill), 1 block (stream copy), >=2 (accum).
// All streaming traffic non-temporal (no reuse; working set > L3).
__global__ __launch_bounds__(256) void k_dense(const f32x4* __restrict__ bv4,
                                               const int* __restrict__ ws_i,
                                               f32x4* __restrict__ out4) {
    const int cell = blockIdx.x >> 2;
    const int chunk = blockIdx.x & 3;
    const int R = cell >> 6;
    const int C = cell & (GRIDN - 1);
    const int start = ws_i[WS_OFFS + cell];
    const int end = ws_i[WS_OFFS + cell + 1];
    const int tbase = chunk * 2048 + threadIdx.x;
    const size_t obase = (size_t)R * 64 * ROWSTRIDE4 + (size_t)C * 128;
    const int cnt = end - start;

    if (cnt == 0) {
        const f32x4 z = {0.f, 0.f, 0.f, 0.f};
#pragma unroll
        for (int i = 0; i < 8; ++i) {
            int t = tbase + i * 256;
            __builtin_nontemporal_store(z, &out4[obase + (size_t)(t >> 7) * ROWSTRIDE4 + (t & 127)]);
        }
    } else if (cnt == 1) {
        const f32x4* __restrict__ src = bv4 + (size_t)ws_i[WS_LIST + start] * BVEC;
#pragma unroll
        for (int i = 0; i < 8; ++i) {
            int t = tbase + i * 256;
            f32x4 v = __builtin_nontemporal_load(&src[t]);
            __builtin_nontemporal_store(v, &out4[obase + (size_t)(t >> 7) * ROWSTRIDE4 + (t & 127)]);
        }
    } else {
        f32x4 acc[8];
#pragma unroll
        for (int i = 0; i < 8; ++i) acc[i] = (f32x4){0.f, 0.f, 0.f, 0.f};
        for (int j = start; j < end; ++j) {
            const f32x4* __restrict__ src = bv4 + (size_t)ws_i[WS_LIST + j] * BVEC;
#pragma unroll
            for (int i = 0; i < 8; ++i)
                acc[i] += __builtin_nontemporal_load(&src[tbase + i * 256]);
        }
#pragma unroll
        for (int i = 0; i < 8; ++i) {
            int t = tbase + i * 256;
            __builtin_nontemporal_store(acc[i], &out4[obase + (size_t)(t >> 7) * ROWSTRIDE4 + (t & 127)]);
        }
    }
}

// ---------------------------------------------------------------------------
extern "C" void kernel_launch(void* const* d_in, const int* in_sizes, int n_in,
                              void* d_out, int out_size, void* d_ws, size_t ws_size,
                              hipStream_t stream) {
    const float* bv = (const float*)d_in[0];
    const void* idx = d_in[1];
    const int N = in_sizes[1] / 2;  // 2048 blocks

    int* ws_i = (int*)d_ws;

    k_setup<<<1, 1024, 0, stream>>>(idx, N, ws_i);
    k_dense<<<NCELLS * 4, 256, 0, stream>>>((const f32x4*)bv, ws_i,
                                            (f32x4*)d_out);
}